// Round 8
// baseline (5939.908 us; speedup 1.0000x reference)
//
#include <hip/hip_runtime.h>
#include <hip/hip_bf16.h>

typedef __attribute__((ext_vector_type(4))) float f4;
typedef __attribute__((ext_vector_type(4))) float f32x4;
typedef __attribute__((ext_vector_type(8))) short bf16x8;
typedef unsigned long long ull;

// ---------------- workspace layout (bytes) ----------------
#define OFF_XCAT   0ull                 // ushort [1024][128][512]  time-major LSTM input
#define OFF_WCAT   134217728ull         // ushort [2048][1024]      packed LSTM weights
#define OFF_BIAS   138412032ull         // float  [2048]
#define OFF_HBUF   138420224ull         // ushort [2][8][16][512]   double-buffered h exchange
#define OFF_FLAG   138682368ull         // uint   [8][32]           per-WG step flags
#define OFF_CTR    138686464ull         // uint   [256]             counters/diag
#define OFF_TST    138687488ull         // uint   [8][32]+pad       exchange self-test scratch
#define WS_NEED    138691584ull

__device__ inline unsigned short f2bf(float x){
  unsigned u = __float_as_uint(x);
  unsigned r = (u + 0x7FFFu + ((u >> 16) & 1u)) >> 16;   // RNE
  return (unsigned short)r;
}
__device__ inline float bf2f(unsigned short s){ return __uint_as_float(((unsigned)s) << 16); }

// ---------------- diagnostic fill (absmax is the debug channel) ----------------
__global__ void __launch_bounds__(256) diag_write(float* out, float val){
  out[blockIdx.x * 256 + threadIdx.x] = val;
}

// ---------------- weight repack ----------------
__global__ void __launch_bounds__(256) prep_w(
    const float* Wii, const float* Wif, const float* Wig, const float* Wio,
    const float* Whi, const float* Whf, const float* Whg, const float* Who,
    const float* Bii, const float* Bif, const float* Big, const float* Bio,
    const float* Bhi, const float* Bhf, const float* Bhg, const float* Bho,
    unsigned short* Wcat, float* bias_cat){
  int e = blockIdx.x * 256 + threadIdx.x;        // < 2048*1024
  int col = e >> 10, k = e & 1023;
  int u = col >> 2, g = col & 3;
  float v;
  if (k < 512){
    const float* p = (g==0)?Wii:((g==1)?Wif:((g==2)?Wig:Wio));
    v = p[u*512 + k];
  } else {
    const float* p = (g==0)?Whi:((g==1)?Whf:((g==2)?Whg:Who));
    v = p[u*512 + (k-512)];
  }
  Wcat[e] = f2bf(v);
  if (e < 2048){
    int u2 = e >> 2, g2 = e & 3;
    const float* bx = (g2==0)?Bii:((g2==1)?Bif:((g2==2)?Big:Bio));
    const float* bh = (g2==0)?Bhi:((g2==1)?Bhf:((g2==2)?Bhg:Bho));
    bias_cat[e] = bx[u2] + bh[u2];
  }
}

// ---------------- fused stage A (proven r2/r3) ----------------
__global__ void __launch_bounds__(256) stageA_fused(
    const float* __restrict__ xnum, const int* __restrict__ xstate,
    const float* __restrict__ emb,
    const float* __restrict__ num_w0, const float* __restrict__ num_b0,
    const float* __restrict__ num_w1, const float* __restrict__ num_b1,
    const float* __restrict__ st_w0,  const float* __restrict__ st_b0,
    const float* __restrict__ st_w1,  const float* __restrict__ st_b1,
    unsigned short* __restrict__ Xcat){
  __shared__ float Wt[32*256];
  __shared__ float xb[16*68];
  __shared__ float h1[16*260];
  int tid = threadIdx.x;
  long tok0 = (long)blockIdx.x * 16;
  int tg = tid >> 6, c4 = tid & 63;

  #pragma unroll 1
  for (int br = 0; br < 2; ++br){
    const float* W0 = br ? st_w0 : num_w0;
    const float* b0 = br ? st_b0 : num_b0;
    const float* W1 = br ? st_w1 : num_w1;
    const float* b1 = br ? st_b1 : num_b1;

    __syncthreads();
    if (br == 0){
      int tk = tid >> 4, q = tid & 15;
      f4 v = *(const f4*)(xnum + (tok0+tk)*64 + q*4);
      float* d = xb + tk*68 + q*4;
      d[0]=v.x; d[1]=v.y; d[2]=v.z; d[3]=v.w;
    } else {
      int tk = tid >> 4, j = tid & 15;
      int idx = xstate[(tok0+tk)*16 + j];
      f4 v = *(const f4*)(emb + idx*4);
      float* d = xb + tk*68 + j*4;
      d[0]=v.x; d[1]=v.y; d[2]=v.z; d[3]=v.w;
    }

    float acc[4][4];
    { f4 bv = *(const f4*)(b0 + c4*4);
      #pragma unroll
      for (int j=0;j<4;j++){ acc[j][0]=bv.x; acc[j][1]=bv.y; acc[j][2]=bv.z; acc[j][3]=bv.w; } }
    for (int kh=0; kh<2; ++kh){
      __syncthreads();
      { int c = tid;
        const f4* src = (const f4*)(W0 + c*64 + kh*32);
        #pragma unroll
        for (int q=0;q<8;q++){
          f4 v = src[q];
          Wt[(q*4+0)*256 + c] = v.x; Wt[(q*4+1)*256 + c] = v.y;
          Wt[(q*4+2)*256 + c] = v.z; Wt[(q*4+3)*256 + c] = v.w;
        }
      }
      __syncthreads();
      for (int kq=0; kq<8; kq++){
        int k0 = kh*32 + kq*4;
        f4 a0 = *(const f4*)(xb + (tg*4+0)*68 + k0);
        f4 a1 = *(const f4*)(xb + (tg*4+1)*68 + k0);
        f4 a2 = *(const f4*)(xb + (tg*4+2)*68 + k0);
        f4 a3 = *(const f4*)(xb + (tg*4+3)*68 + k0);
        f4 w0 = *(const f4*)(Wt + (kq*4+0)*256 + c4*4);
        f4 w1 = *(const f4*)(Wt + (kq*4+1)*256 + c4*4);
        f4 w2 = *(const f4*)(Wt + (kq*4+2)*256 + c4*4);
        f4 w3 = *(const f4*)(Wt + (kq*4+3)*256 + c4*4);
        #pragma unroll
        for (int j=0;j<4;j++){
          f4 a = (j==0)?a0:((j==1)?a1:((j==2)?a2:a3));
          #pragma unroll
          for (int d=0; d<4; d++)
            acc[j][d] += a.x*w0[d] + a.y*w1[d] + a.z*w2[d] + a.w*w3[d];
        }
      }
    }
    #pragma unroll
    for (int j=0;j<4;j++){
      float v0=fmaxf(acc[j][0],0.f), v1=fmaxf(acc[j][1],0.f);
      float v2=fmaxf(acc[j][2],0.f), v3=fmaxf(acc[j][3],0.f);
      float s1 = v0+v1+v2+v3, s2 = v0*v0+v1*v1+v2*v2+v3*v3;
      for (int off=1; off<64; off<<=1){ s1 += __shfl_xor(s1, off); s2 += __shfl_xor(s2, off); }
      float mu = s1 * (1.f/256.f);
      float rs = rsqrtf(s2*(1.f/256.f) - mu*mu + 1e-5f);
      f4 o; o.x=(v0-mu)*rs; o.y=(v1-mu)*rs; o.z=(v2-mu)*rs; o.w=(v3-mu)*rs;
      *(f4*)(h1 + (tg*4+j)*260 + c4*4) = o;
    }

    float ac2[4][4];
    { f4 bv = *(const f4*)(b1 + c4*4);
      #pragma unroll
      for (int j=0;j<4;j++){ ac2[j][0]=bv.x; ac2[j][1]=bv.y; ac2[j][2]=bv.z; ac2[j][3]=bv.w; } }
    for (int kh=0; kh<8; ++kh){
      __syncthreads();
      { int c = tid;
        const f4* src = (const f4*)(W1 + c*256 + kh*32);
        #pragma unroll
        for (int q=0;q<8;q++){
          f4 v = src[q];
          Wt[(q*4+0)*256 + c] = v.x; Wt[(q*4+1)*256 + c] = v.y;
          Wt[(q*4+2)*256 + c] = v.z; Wt[(q*4+3)*256 + c] = v.w;
        }
      }
      __syncthreads();
      for (int kq=0; kq<8; kq++){
        int k0 = kh*32 + kq*4;
        f4 a0 = *(const f4*)(h1 + (tg*4+0)*260 + k0);
        f4 a1 = *(const f4*)(h1 + (tg*4+1)*260 + k0);
        f4 a2 = *(const f4*)(h1 + (tg*4+2)*260 + k0);
        f4 a3 = *(const f4*)(h1 + (tg*4+3)*260 + k0);
        f4 w0 = *(const f4*)(Wt + (kq*4+0)*256 + c4*4);
        f4 w1 = *(const f4*)(Wt + (kq*4+1)*256 + c4*4);
        f4 w2 = *(const f4*)(Wt + (kq*4+2)*256 + c4*4);
        f4 w3 = *(const f4*)(Wt + (kq*4+3)*256 + c4*4);
        #pragma unroll
        for (int j=0;j<4;j++){
          f4 a = (j==0)?a0:((j==1)?a1:((j==2)?a2:a3));
          #pragma unroll
          for (int d=0; d<4; d++)
            ac2[j][d] += a.x*w0[d] + a.y*w1[d] + a.z*w2[d] + a.w*w3[d];
        }
      }
    }
    #pragma unroll
    for (int j=0;j<4;j++){
      float v0=fmaxf(ac2[j][0],0.f), v1=fmaxf(ac2[j][1],0.f);
      float v2=fmaxf(ac2[j][2],0.f), v3=fmaxf(ac2[j][3],0.f);
      float s1 = v0+v1+v2+v3, s2 = v0*v0+v1*v1+v2*v2+v3*v3;
      for (int off=1; off<64; off<<=1){ s1 += __shfl_xor(s1, off); s2 += __shfl_xor(s2, off); }
      float mu = s1 * (1.f/256.f);
      float rs = rsqrtf(s2*(1.f/256.f) - mu*mu + 1e-5f);
      long tok = tok0 + tg*4 + j;
      long bb = tok >> 10, ss = tok & 1023;
      unsigned short* o = Xcat + (ss*128 + bb)*512 + br*256 + c4*4;
      unsigned lo = (unsigned)f2bf((v0-mu)*rs) | ((unsigned)f2bf((v1-mu)*rs) << 16);
      unsigned hi = (unsigned)f2bf((v2-mu)*rs) | ((unsigned)f2bf((v3-mu)*rs) << 16);
      ((unsigned*)o)[0] = lo; ((unsigned*)o)[1] = hi;
    }
  }
}

// ---------------- exchange primitives ----------------
// LOCAL (same XCD): publish via un-flagged HW atomics (execute at XCD L2 — cannot
// linger in L0); consume via buffer_inv sc0 (L0 flash-inv) + plain loads (hit L2).
__device__ __forceinline__ void atomic_swap_l2(unsigned int* p, unsigned v){
  asm volatile("global_atomic_swap %0, %1, off" :: "v"(p), "v"(v) : "memory");
}
__device__ __forceinline__ unsigned poll1_inv(const unsigned int* p){
  unsigned a;
  asm volatile("buffer_inv sc0" ::: "memory");
  asm volatile("global_load_dword %0, %1, off\n\ts_waitcnt vmcnt(0)"
               : "=v"(a) : "v"(p) : "memory");
  return a;
}
// issue 8x8B plain loads, stride 128B, NO wait
__device__ __forceinline__ void ld8_issue(const void* p, ull* v){
  asm volatile(
    "global_load_dwordx2 %0, %8, off\n\t"
    "global_load_dwordx2 %1, %8, off offset:128\n\t"
    "global_load_dwordx2 %2, %8, off offset:256\n\t"
    "global_load_dwordx2 %3, %8, off offset:384\n\t"
    "global_load_dwordx2 %4, %8, off offset:512\n\t"
    "global_load_dwordx2 %5, %8, off offset:640\n\t"
    "global_load_dwordx2 %6, %8, off offset:768\n\t"
    "global_load_dwordx2 %7, %8, off offset:896"
    : "=&v"(v[0]),"=&v"(v[1]),"=&v"(v[2]),"=&v"(v[3]),
      "=&v"(v[4]),"=&v"(v[5]),"=&v"(v[6]),"=&v"(v[7])
    : "v"(p) : "memory");
}

// ---------------- LOCAL (XCD-L2) step loop ----------------
__device__ __forceinline__ void lstm_local(
    int g, int m, int w, int lane, int tid,
    const unsigned short* __restrict__ Xcat,
    const bf16x8 (&wf)[32], f32x4 bias4,
    unsigned int* hbuf32, unsigned int* flags, unsigned int* ctr,
    char* actb, volatile int* sdead)
{
  float cst = 0.f;
  int r16 = tid >> 4, q16 = tid & 15;
  const unsigned int* fl = flags + g*32;
  unsigned int* myflag = flags + g*32 + m;

  for (int t=0; t<1024; ++t){
    // x B-fragments to registers
    bf16x8 xf[16];
    {
      const bf16x8* xsrc = (const bf16x8*)(Xcat + ((long)t*128 + g*16 + (lane&15))*512 + (lane>>4)*8);
      #pragma unroll
      for (int s=0;s<16;s++) xf[s] = xsrc[s*4];
    }
    // x-part MFMAs (k=0..511)
    f32x4 acc0 = bias4;
    f32x4 acc1; acc1.x=0.f; acc1.y=0.f; acc1.z=0.f; acc1.w=0.f;
    #pragma unroll
    for (int s=0;s<16;s+=2){
      acc0 = __builtin_amdgcn_mfma_f32_16x16x32_bf16(wf[s],   xf[s],   acc0, 0, 0, 0);
      acc1 = __builtin_amdgcn_mfma_f32_16x16x32_bf16(wf[s+1], xf[s+1], acc1, 0, 0, 0);
    }
    // all-wave poll of the 32 per-WG flags at L2 (no convergence barrier needed)
    if (t > 0){
      unsigned tt = (unsigned)t; int itc = 0;
      const unsigned int* fp = fl + (lane & 31);
      for (;;){
        unsigned a = poll1_inv(fp);
        if (__all((int)(a >= tt))) break;
        if ((itc & 63) == 63 && *sdead) break;
        if (++itc > 20000){
          *sdead = 1;
          if (lane == 0 && w == 0)
            __hip_atomic_store(&ctr[252], 4096u + tt, __ATOMIC_RELAXED, __HIP_MEMORY_SCOPE_AGENT);
          break;
        }
      }
    }
    // h read: plain loads (L0 already invalidated) -> swizzled LDS (double buffer)
    {
      const char* hbase = (const char*)hbuf32 + (long)(t&1)*131072 + g*16384 + r16*1024 + q16*8;
      ull hv[8];
      ld8_issue(hbase, hv);
      asm volatile("s_waitcnt vmcnt(0)" ::: "memory");
      __builtin_amdgcn_sched_barrier(0);
      char* hl = actb + (t&1)*16384;
      #pragma unroll
      for (int i=0;i<8;i++){
        int byt = (r16*1024 + q16*8 + i*128) ^ ((r16 & 7) << 4);
        *(ull*)(hl + byt) = hv[i];
      }
    }
    __syncthreads();
    if (*sdead) break;
    // h-part MFMAs (k=512..1023)
    {
      const char* hl = actb + (t&1)*16384;
      #pragma unroll
      for (int s=0;s<16;s+=2){
        int by0 = ((lane&15)*1024 + s*64     + (lane>>4)*16) ^ (((lane&15)&7) << 4);
        int by1 = ((lane&15)*1024 + (s+1)*64 + (lane>>4)*16) ^ (((lane&15)&7) << 4);
        bf16x8 b0 = *(const bf16x8*)(hl + by0);
        bf16x8 b1 = *(const bf16x8*)(hl + by1);
        acc0 = __builtin_amdgcn_mfma_f32_16x16x32_bf16(wf[16+s], b0, acc0, 0, 0, 0);
        acc1 = __builtin_amdgcn_mfma_f32_16x16x32_bf16(wf[17+s], b1, acc1, 0, 0, 0);
      }
    }
    // gates & state update
    float gi = acc0.x + acc1.x, gf = acc0.y + acc1.y;
    float gg = acc0.z + acc1.z, go = acc0.w + acc1.w;
    float iv = 1.f / (1.f + __expf(-gi));
    float fv = 1.f / (1.f + __expf(-gf));
    float e2 = __expf(-2.f * gg);
    float gv = (1.f - e2) / (1.f + e2);
    float ov = 1.f / (1.f + __expf(-go));
    cst = fv * cst + iv * gv;
    float e2c = __expf(-2.f * cst);
    float hout = ov * (1.f - e2c) / (1.f + e2c);
    // publish h via L2 atomics (guaranteed visible to same-XCD CUs)
    {
      unsigned short hb16 = f2bf(hout);
      int partner = __shfl_xor((int)hb16, 16);
      int hi = lane >> 4;
      if ((hi & 1) == 0){
        int ug = 16*m + 4*w + hi;
        int r = lane & 15;
        unsigned pack = (unsigned)hb16 | (((unsigned)partner & 0xFFFFu) << 16);
        unsigned int* dst = hbuf32 + ((long)((t+1)&1)*8 + g)*(16*256) + r*256 + (ug >> 1);
        atomic_swap_l2(dst, pack);
      }
    }
    asm volatile("s_waitcnt vmcnt(0)" ::: "memory");
    __syncthreads();
    if (tid == 0) atomic_swap_l2(myflag, (unsigned)(t+1));
  }
}

// ---------------- fallback (agent-scope) step loop — byte-identical to r7 ----------------
__device__ __forceinline__ void lstm_agent(
    int g, int m, int w, int lane, int tid,
    const unsigned short* __restrict__ Xcat,
    const bf16x8 (&wf)[32], f32x4 bias4,
    unsigned int* hbuf32, unsigned int* flags, unsigned int* ctr,
    char* actb, volatile int* sdead)
{
  float cst = 0.f;
  int r16 = tid >> 4, q16 = tid & 15;
  const unsigned int* fl = flags + g*32;
  unsigned int* myflag = flags + g*32 + m;

  for (int t=0; t<1024; ++t){
    bf16x8 xf[16];
    {
      const bf16x8* xsrc = (const bf16x8*)(Xcat + ((long)t*128 + g*16 + (lane&15))*512 + (lane>>4)*8);
      #pragma unroll
      for (int s=0;s<16;s++) xf[s] = xsrc[s*4];
    }
    f32x4 acc0 = bias4;
    f32x4 acc1; acc1.x=0.f; acc1.y=0.f; acc1.z=0.f; acc1.w=0.f;
    #pragma unroll
    for (int s=0;s<16;s+=2){
      acc0 = __builtin_amdgcn_mfma_f32_16x16x32_bf16(wf[s],   xf[s],   acc0, 0, 0, 0);
      acc1 = __builtin_amdgcn_mfma_f32_16x16x32_bf16(wf[s+1], xf[s+1], acc1, 0, 0, 0);
    }
    if (t > 0 && w == 0){
      unsigned tt = (unsigned)t; int itc = 0;
      for (;;){
        unsigned a = __hip_atomic_load(&fl[lane & 31], __ATOMIC_RELAXED, __HIP_MEMORY_SCOPE_AGENT);
        if (__all((int)(a >= tt))) break;
        if (++itc > 400000){
          if (lane == 0){
            *sdead = 1;
            __hip_atomic_store(&ctr[252], tt, __ATOMIC_RELAXED, __HIP_MEMORY_SCOPE_AGENT);
          }
          break;
        }
      }
      asm volatile("" ::: "memory");
    }
    __syncthreads();
    if (*sdead) break;
    {
      const ull* hb = (const ull*)hbuf32 + ((long)(t&1)*8 + g)*(16*128) + r16*128 + q16;
      char* hl = actb + (t&1)*16384;
      ull hv[8];
      #pragma unroll
      for (int i=0;i<8;i++)
        hv[i] = __hip_atomic_load(&hb[i*16], __ATOMIC_RELAXED, __HIP_MEMORY_SCOPE_AGENT);
      #pragma unroll
      for (int i=0;i<8;i++){
        int byt = (r16*1024 + q16*8 + i*128) ^ ((r16 & 7) << 4);
        *(ull*)(hl + byt) = hv[i];
      }
    }
    __syncthreads();
    {
      const char* hl = actb + (t&1)*16384;
      #pragma unroll
      for (int s=0;s<16;s+=2){
        int by0 = ((lane&15)*1024 + s*64     + (lane>>4)*16) ^ (((lane&15)&7) << 4);
        int by1 = ((lane&15)*1024 + (s+1)*64 + (lane>>4)*16) ^ (((lane&15)&7) << 4);
        bf16x8 b0 = *(const bf16x8*)(hl + by0);
        bf16x8 b1 = *(const bf16x8*)(hl + by1);
        acc0 = __builtin_amdgcn_mfma_f32_16x16x32_bf16(wf[16+s], b0, acc0, 0, 0, 0);
        acc1 = __builtin_amdgcn_mfma_f32_16x16x32_bf16(wf[17+s], b1, acc1, 0, 0, 0);
      }
    }
    float gi = acc0.x + acc1.x, gf = acc0.y + acc1.y;
    float gg = acc0.z + acc1.z, go = acc0.w + acc1.w;
    float iv = 1.f / (1.f + __expf(-gi));
    float fv = 1.f / (1.f + __expf(-gf));
    float e2 = __expf(-2.f * gg);
    float gv = (1.f - e2) / (1.f + e2);
    float ov = 1.f / (1.f + __expf(-go));
    cst = fv * cst + iv * gv;
    float e2c = __expf(-2.f * cst);
    float hout = ov * (1.f - e2c) / (1.f + e2c);
    {
      unsigned short hb16 = f2bf(hout);
      int partner = __shfl_xor((int)hb16, 16);
      int hi = lane >> 4;
      if ((hi & 1) == 0){
        int ug = 16*m + 4*w + hi;
        int r = lane & 15;
        unsigned pack = (unsigned)hb16 | (((unsigned)partner & 0xFFFFu) << 16);
        unsigned int* dst = hbuf32 + ((long)((t+1)&1)*8 + g)*(16*256) + r*256 + (ug >> 1);
        __hip_atomic_store(dst, pack, __ATOMIC_RELAXED, __HIP_MEMORY_SCOPE_AGENT);
      }
    }
    asm volatile("s_waitcnt vmcnt(0)" ::: "memory");
    __syncthreads();
    if (tid == 0)
      __hip_atomic_store(myflag, (unsigned)(t+1), __ATOMIC_RELAXED, __HIP_MEMORY_SCOPE_AGENT);
  }
}

// ---------------- persistent LSTM kernel ----------------
// Consensus #1: distribution check (32 WGs/XCD). If ok, bounded self-test of the
// L2 exchange primitive; consensus #2 picks the FINAL mode globally. Any failure
// -> r7-proven agent-scope fallback.
__global__ void __launch_bounds__(256, 1) lstm_pk(
    const unsigned short* __restrict__ Xcat,
    const unsigned short* __restrict__ Wcat,
    const float* __restrict__ bias_cat,
    unsigned int* __restrict__ hbuf32,
    unsigned int* __restrict__ flags,
    unsigned int* __restrict__ ctr,
    unsigned int* __restrict__ tst){
  __shared__ __align__(16) char actb[32768];
  __shared__ int okf, sdead, sgm, tokk;
  int tid = threadIdx.x;
  int lane = tid & 63, w = tid >> 6;

  if (tid == 0){
    unsigned xcc;
    asm volatile("s_getreg_b32 %0, hwreg(HW_REG_XCC_ID)" : "=s"(xcc));
    xcc &= 7u;
    unsigned slot = __hip_atomic_fetch_add(&ctr[240+xcc], 1u, __ATOMIC_RELAXED, __HIP_MEMORY_SCOPE_AGENT);
    sgm = (int)(xcc*32u + (slot & 31u));
    unsigned arr = __hip_atomic_fetch_add(&ctr[255], 1u, __ATOMIC_ACQ_REL, __HIP_MEMORY_SCOPE_AGENT);
    if (arr == 255u){
      int all32 = 1;
      for (int x=0; x<8; x++){
        unsigned c = __hip_atomic_load(&ctr[240+x], __ATOMIC_ACQUIRE, __HIP_MEMORY_SCOPE_AGENT);
        if (c != 32u) all32 = 0;
      }
      __hip_atomic_store(&ctr[249], all32 ? 2u : 1u, __ATOMIC_RELEASE, __HIP_MEMORY_SCOPE_AGENT);
    }
    unsigned md = 0; int it = 0;
    do {
      md = __hip_atomic_load(&ctr[249], __ATOMIC_ACQUIRE, __HIP_MEMORY_SCOPE_AGENT);
      if (md) break;
      __builtin_amdgcn_s_sleep(8);
    } while (++it < 2000000);
    okf = (int)md;
    sdead = 0; tokk = 0;
  }
  __syncthreads();
  int mode = okf;
  if (mode == 0) return;

  int g, m;
  if (mode == 2){ g = sgm >> 5; m = sgm & 31; }
  else          { g = blockIdx.x & 7; m = blockIdx.x >> 3; }

  // ---- self-test of the L2 exchange primitive (only if XCD grouping holds) ----
  if (mode == 2){
    if (tid == 0){
      atomic_swap_l2(tst + g*32 + m, 1u);
      asm volatile("s_waitcnt vmcnt(0)" ::: "memory");
    }
    __syncthreads();
    if (w == 0){
      const unsigned int* tp = tst + g*32;
      int okl = 0, itc = 0;
      for (;;){
        unsigned a = poll1_inv(tp + (lane & 31));
        if (__all((int)(a == 1u))){ okl = 1; break; }
        if (++itc > 3000) break;
      }
      if (lane == 0) tokk = okl;
    }
    __syncthreads();
    if (tid == 0){
      if (!tokk)
        __hip_atomic_fetch_add(&ctr[253], 1u, __ATOMIC_RELAXED, __HIP_MEMORY_SCOPE_AGENT);
      unsigned arr = __hip_atomic_fetch_add(&ctr[254], 1u, __ATOMIC_ACQ_REL, __HIP_MEMORY_SCOPE_AGENT);
      if (arr == 255u){
        unsigned f = __hip_atomic_load(&ctr[253], __ATOMIC_ACQUIRE, __HIP_MEMORY_SCOPE_AGENT);
        __hip_atomic_store(&ctr[248], f ? 1u : 2u, __ATOMIC_RELEASE, __HIP_MEMORY_SCOPE_AGENT);
      }
      unsigned md2 = 0; int it = 0;
      do {
        md2 = __hip_atomic_load(&ctr[248], __ATOMIC_ACQUIRE, __HIP_MEMORY_SCOPE_AGENT);
        if (md2) break;
        __builtin_amdgcn_s_sleep(8);
      } while (++it < 2000000);
      okf = (int)md2;
    }
    __syncthreads();
    mode = okf;
    if (mode == 0) return;
    if (mode == 1){ g = blockIdx.x & 7; m = blockIdx.x >> 3; }
  }

  // stationary weights (after final g,m known)
  int colg = 64*m + 16*w + (lane & 15);
  bf16x8 wf[32];
  {
    const bf16x8* wsrc = (const bf16x8*)(Wcat + colg*1024 + (lane>>4)*8);
    #pragma unroll
    for (int s=0;s<32;s++) wf[s] = wsrc[s*4];
  }
  int cb = 64*m + 16*w + 4*(lane>>4);
  f32x4 bias4;
  bias4.x = bias_cat[cb+0]; bias4.y = bias_cat[cb+1];
  bias4.z = bias_cat[cb+2]; bias4.w = bias_cat[cb+3];

  if (mode == 2)
    lstm_local(g, m, w, lane, tid, Xcat, wf, bias4, hbuf32, flags, ctr, actb, (volatile int*)&sdead);
  else
    lstm_agent(g, m, w, lane, tid, Xcat, wf, bias4, hbuf32, flags, ctr, actb, (volatile int*)&sdead);

  __syncthreads();
  if (tid == 0 && !sdead)
    __hip_atomic_fetch_add(&ctr[251], 1u, __ATOMIC_RELAXED, __HIP_MEMORY_SCOPE_AGENT);
}

// ---------------- output projection ----------------
__global__ void __launch_bounds__(256) out_gemm(
    const unsigned short* __restrict__ hbuf, const unsigned int* __restrict__ ctr,
    const float* __restrict__ out_w, const float* __restrict__ out_b,
    float* __restrict__ out){
  unsigned done = ctr[251], arriv = ctr[255], dead = ctr[252];
  if (dead != 0u || done != 256u){
    // bands: 20001+ agent deadlock | 24097+ local deadlock | ~10xxx not co-resident
    float v = dead ? (20000.f + (float)dead) : (10000.f + (float)arriv);
    if (threadIdx.x < 32) out[blockIdx.x*32 + threadIdx.x] = v;
    return;
  }
  __shared__ float part[8][32];
  int b = blockIdx.x;
  int g = b >> 4, r = b & 15;
  const unsigned short* hrow = hbuf + ((long)g*16 + r)*512;   // buf 0 holds h after step 1023
  int col = threadIdx.x & 31, p = threadIdx.x >> 5;
  float s = 0.f;
  for (int u = p*64; u < p*64 + 64; ++u)
    s += bf2f(hrow[u]) * out_w[col*512 + u];
  part[p][col] = s;
  __syncthreads();
  if (p == 0){
    float t = out_b[col];
    #pragma unroll
    for (int i=0;i<8;i++) t += part[i][col];
    out[b*32 + col] = t;
  }
}

extern "C" void kernel_launch(void* const* d_in, const int* in_sizes, int n_in,
                              void* d_out, int out_size, void* d_ws, size_t ws_size,
                              hipStream_t stream){
  const float* x_num   = (const float*)d_in[0];
  const int*   x_state = (const int*)d_in[1];
  const float* num_w0  = (const float*)d_in[2];
  const float* num_b0  = (const float*)d_in[3];
  const float* num_w1  = (const float*)d_in[4];
  const float* num_b1  = (const float*)d_in[5];
  const float* emb     = (const float*)d_in[6];
  const float* st_w0   = (const float*)d_in[7];
  const float* st_b0   = (const float*)d_in[8];
  const float* st_w1   = (const float*)d_in[9];
  const float* st_b1   = (const float*)d_in[10];
  const float* Wii = (const float*)d_in[11];
  const float* Whi = (const float*)d_in[12];
  const float* Wif = (const float*)d_in[13];
  const float* Whf = (const float*)d_in[14];
  const float* Wig = (const float*)d_in[15];
  const float* Whg = (const float*)d_in[16];
  const float* Wio = (const float*)d_in[17];
  const float* Who = (const float*)d_in[18];
  const float* Bii = (const float*)d_in[19];
  const float* Bhi = (const float*)d_in[20];
  const float* Bif = (const float*)d_in[21];
  const float* Bhf = (const float*)d_in[22];
  const float* Big = (const float*)d_in[23];
  const float* Bhg = (const float*)d_in[24];
  const float* Bio = (const float*)d_in[25];
  const float* Bho = (const float*)d_in[26];
  const float* out_w = (const float*)d_in[27];
  const float* out_b = (const float*)d_in[28];

  float* out = (float*)d_out;

  // sentinel: if later launches silently fail, absmax ~= 50000
  diag_write<<<16, 256, 0, stream>>>(out, 50000.f);

  if (ws_size < WS_NEED){
    diag_write<<<16, 256, 0, stream>>>(out, 100000.f + (float)(ws_size >> 20));
    return;
  }

  char* ws = (char*)d_ws;
  unsigned short* Xcat = (unsigned short*)(ws + OFF_XCAT);
  unsigned short* Wcat = (unsigned short*)(ws + OFF_WCAT);
  float* bias_cat      = (float*)(ws + OFF_BIAS);
  unsigned int* hbuf32 = (unsigned int*)(ws + OFF_HBUF);
  unsigned int* flags  = (unsigned int*)(ws + OFF_FLAG);
  unsigned int* ctr    = (unsigned int*)(ws + OFF_CTR);
  unsigned int* tst    = (unsigned int*)(ws + OFF_TST);

  // zero h double-buffer + flags + counters + test scratch (graph-replay determinism)
  hipMemsetAsync(ws + OFF_HBUF, 0, 262144 + 4096 + 1024 + 4096, stream);

  prep_w<<<8192, 256, 0, stream>>>(Wii, Wif, Wig, Wio, Whi, Whf, Whg, Who,
                                   Bii, Bif, Big, Bio, Bhi, Bhf, Bhg, Bho,
                                   Wcat, bias_cat);

  stageA_fused<<<8192, 256, 0, stream>>>(x_num, x_state, emb,
                                         num_w0, num_b0, num_w1, num_b1,
                                         st_w0, st_b0, st_w1, st_b1, Xcat);

  lstm_pk<<<256, 256, 0, stream>>>(Xcat, Wcat, bias_cat, hbuf32, flags, ctr, tst);

  out_gemm<<<128, 256, 0, stream>>>((const unsigned short*)hbuf32, ctr, out_w, out_b, out);
}

// Round 9
// 5467.482 us; speedup vs baseline: 1.0864x; 1.0864x over previous
//
#include <hip/hip_runtime.h>
#include <hip/hip_bf16.h>

typedef __attribute__((ext_vector_type(4))) float f4;
typedef __attribute__((ext_vector_type(4))) float f32x4;
typedef __attribute__((ext_vector_type(8))) short bf16x8;
typedef unsigned long long ull;

// ---------------- workspace layout (bytes) ----------------
#define OFF_XCAT   0ull                 // ushort [1024][128][512]  time-major LSTM input
#define OFF_WCAT   134217728ull         // ushort [2048][1024]      packed LSTM weights
#define OFF_BIAS   138412032ull         // float  [2048]
#define OFF_HBUF   138420224ull         // ushort [2][8][16][512]   double-buffered h exchange
#define OFF_FLAG   138682368ull         // ull    [8][128]          per-producer-wave step flags (8B stride)
#define OFF_CTR    138690560ull         // uint   [256]             counters/diag
#define WS_NEED    138691584ull

__device__ inline unsigned short f2bf(float x){
  unsigned u = __float_as_uint(x);
  unsigned r = (u + 0x7FFFu + ((u >> 16) & 1u)) >> 16;   // RNE
  return (unsigned short)r;
}
__device__ inline float bf2f(unsigned short s){ return __uint_as_float(((unsigned)s) << 16); }

// ---------------- diagnostic fill (absmax is the debug channel) ----------------
__global__ void __launch_bounds__(256) diag_write(float* out, float val){
  out[blockIdx.x * 256 + threadIdx.x] = val;
}

// ---------------- weight repack ----------------
__global__ void __launch_bounds__(256) prep_w(
    const float* Wii, const float* Wif, const float* Wig, const float* Wio,
    const float* Whi, const float* Whf, const float* Whg, const float* Who,
    const float* Bii, const float* Bif, const float* Big, const float* Bio,
    const float* Bhi, const float* Bhf, const float* Bhg, const float* Bho,
    unsigned short* Wcat, float* bias_cat){
  int e = blockIdx.x * 256 + threadIdx.x;        // < 2048*1024
  int col = e >> 10, k = e & 1023;
  int u = col >> 2, g = col & 3;
  float v;
  if (k < 512){
    const float* p = (g==0)?Wii:((g==1)?Wif:((g==2)?Wig:Wio));
    v = p[u*512 + k];
  } else {
    const float* p = (g==0)?Whi:((g==1)?Whf:((g==2)?Whg:Who));
    v = p[u*512 + (k-512)];
  }
  Wcat[e] = f2bf(v);
  if (e < 2048){
    int u2 = e >> 2, g2 = e & 3;
    const float* bx = (g2==0)?Bii:((g2==1)?Bif:((g2==2)?Big:Bio));
    const float* bh = (g2==0)?Bhi:((g2==1)?Bhf:((g2==2)?Bhg:Bho));
    bias_cat[e] = bx[u2] + bh[u2];
  }
}

// ---------------- fused stage A (proven r2/r3) ----------------
__global__ void __launch_bounds__(256) stageA_fused(
    const float* __restrict__ xnum, const int* __restrict__ xstate,
    const float* __restrict__ emb,
    const float* __restrict__ num_w0, const float* __restrict__ num_b0,
    const float* __restrict__ num_w1, const float* __restrict__ num_b1,
    const float* __restrict__ st_w0,  const float* __restrict__ st_b0,
    const float* __restrict__ st_w1,  const float* __restrict__ st_b1,
    unsigned short* __restrict__ Xcat){
  __shared__ float Wt[32*256];
  __shared__ float xb[16*68];
  __shared__ float h1[16*260];
  int tid = threadIdx.x;
  long tok0 = (long)blockIdx.x * 16;
  int tg = tid >> 6, c4 = tid & 63;

  #pragma unroll 1
  for (int br = 0; br < 2; ++br){
    const float* W0 = br ? st_w0 : num_w0;
    const float* b0 = br ? st_b0 : num_b0;
    const float* W1 = br ? st_w1 : num_w1;
    const float* b1 = br ? st_b1 : num_b1;

    __syncthreads();
    if (br == 0){
      int tk = tid >> 4, q = tid & 15;
      f4 v = *(const f4*)(xnum + (tok0+tk)*64 + q*4);
      float* d = xb + tk*68 + q*4;
      d[0]=v.x; d[1]=v.y; d[2]=v.z; d[3]=v.w;
    } else {
      int tk = tid >> 4, j = tid & 15;
      int idx = xstate[(tok0+tk)*16 + j];
      f4 v = *(const f4*)(emb + idx*4);
      float* d = xb + tk*68 + j*4;
      d[0]=v.x; d[1]=v.y; d[2]=v.z; d[3]=v.w;
    }

    float acc[4][4];
    { f4 bv = *(const f4*)(b0 + c4*4);
      #pragma unroll
      for (int j=0;j<4;j++){ acc[j][0]=bv.x; acc[j][1]=bv.y; acc[j][2]=bv.z; acc[j][3]=bv.w; } }
    for (int kh=0; kh<2; ++kh){
      __syncthreads();
      { int c = tid;
        const f4* src = (const f4*)(W0 + c*64 + kh*32);
        #pragma unroll
        for (int q=0;q<8;q++){
          f4 v = src[q];
          Wt[(q*4+0)*256 + c] = v.x; Wt[(q*4+1)*256 + c] = v.y;
          Wt[(q*4+2)*256 + c] = v.z; Wt[(q*4+3)*256 + c] = v.w;
        }
      }
      __syncthreads();
      for (int kq=0; kq<8; kq++){
        int k0 = kh*32 + kq*4;
        f4 a0 = *(const f4*)(xb + (tg*4+0)*68 + k0);
        f4 a1 = *(const f4*)(xb + (tg*4+1)*68 + k0);
        f4 a2 = *(const f4*)(xb + (tg*4+2)*68 + k0);
        f4 a3 = *(const f4*)(xb + (tg*4+3)*68 + k0);
        f4 w0 = *(const f4*)(Wt + (kq*4+0)*256 + c4*4);
        f4 w1 = *(const f4*)(Wt + (kq*4+1)*256 + c4*4);
        f4 w2 = *(const f4*)(Wt + (kq*4+2)*256 + c4*4);
        f4 w3 = *(const f4*)(Wt + (kq*4+3)*256 + c4*4);
        #pragma unroll
        for (int j=0;j<4;j++){
          f4 a = (j==0)?a0:((j==1)?a1:((j==2)?a2:a3));
          #pragma unroll
          for (int d=0; d<4; d++)
            acc[j][d] += a.x*w0[d] + a.y*w1[d] + a.z*w2[d] + a.w*w3[d];
        }
      }
    }
    #pragma unroll
    for (int j=0;j<4;j++){
      float v0=fmaxf(acc[j][0],0.f), v1=fmaxf(acc[j][1],0.f);
      float v2=fmaxf(acc[j][2],0.f), v3=fmaxf(acc[j][3],0.f);
      float s1 = v0+v1+v2+v3, s2 = v0*v0+v1*v1+v2*v2+v3*v3;
      for (int off=1; off<64; off<<=1){ s1 += __shfl_xor(s1, off); s2 += __shfl_xor(s2, off); }
      float mu = s1 * (1.f/256.f);
      float rs = rsqrtf(s2*(1.f/256.f) - mu*mu + 1e-5f);
      f4 o; o.x=(v0-mu)*rs; o.y=(v1-mu)*rs; o.z=(v2-mu)*rs; o.w=(v3-mu)*rs;
      *(f4*)(h1 + (tg*4+j)*260 + c4*4) = o;
    }

    float ac2[4][4];
    { f4 bv = *(const f4*)(b1 + c4*4);
      #pragma unroll
      for (int j=0;j<4;j++){ ac2[j][0]=bv.x; ac2[j][1]=bv.y; ac2[j][2]=bv.z; ac2[j][3]=bv.w; } }
    for (int kh=0; kh<8; ++kh){
      __syncthreads();
      { int c = tid;
        const f4* src = (const f4*)(W1 + c*256 + kh*32);
        #pragma unroll
        for (int q=0;q<8;q++){
          f4 v = src[q];
          Wt[(q*4+0)*256 + c] = v.x; Wt[(q*4+1)*256 + c] = v.y;
          Wt[(q*4+2)*256 + c] = v.z; Wt[(q*4+3)*256 + c] = v.w;
        }
      }
      __syncthreads();
      for (int kq=0; kq<8; kq++){
        int k0 = kh*32 + kq*4;
        f4 a0 = *(const f4*)(h1 + (tg*4+0)*260 + k0);
        f4 a1 = *(const f4*)(h1 + (tg*4+1)*260 + k0);
        f4 a2 = *(const f4*)(h1 + (tg*4+2)*260 + k0);
        f4 a3 = *(const f4*)(h1 + (tg*4+3)*260 + k0);
        f4 w0 = *(const f4*)(Wt + (kq*4+0)*256 + c4*4);
        f4 w1 = *(const f4*)(Wt + (kq*4+1)*256 + c4*4);
        f4 w2 = *(const f4*)(Wt + (kq*4+2)*256 + c4*4);
        f4 w3 = *(const f4*)(Wt + (kq*4+3)*256 + c4*4);
        #pragma unroll
        for (int j=0;j<4;j++){
          f4 a = (j==0)?a0:((j==1)?a1:((j==2)?a2:a3));
          #pragma unroll
          for (int d=0; d<4; d++)
            ac2[j][d] += a.x*w0[d] + a.y*w1[d] + a.z*w2[d] + a.w*w3[d];
        }
      }
    }
    #pragma unroll
    for (int j=0;j<4;j++){
      float v0=fmaxf(ac2[j][0],0.f), v1=fmaxf(ac2[j][1],0.f);
      float v2=fmaxf(ac2[j][2],0.f), v3=fmaxf(ac2[j][3],0.f);
      float s1 = v0+v1+v2+v3, s2 = v0*v0+v1*v1+v2*v2+v3*v3;
      for (int off=1; off<64; off<<=1){ s1 += __shfl_xor(s1, off); s2 += __shfl_xor(s2, off); }
      float mu = s1 * (1.f/256.f);
      float rs = rsqrtf(s2*(1.f/256.f) - mu*mu + 1e-5f);
      long tok = tok0 + tg*4 + j;
      long bb = tok >> 10, ss = tok & 1023;
      unsigned short* o = Xcat + (ss*128 + bb)*512 + br*256 + c4*4;
      unsigned lo = (unsigned)f2bf((v0-mu)*rs) | ((unsigned)f2bf((v1-mu)*rs) << 16);
      unsigned hi = (unsigned)f2bf((v2-mu)*rs) | ((unsigned)f2bf((v3-mu)*rs) << 16);
      ((unsigned*)o)[0] = lo; ((unsigned*)o)[1] = hi;
    }
  }
}

// ---------------- persistent LSTM kernel (agent-scope, per-wave flags, 1 barrier/step) ----------------
// grid = 256 WGs x 256 thr. group g = blockIdx&7 (16 batch rows), member m = blockIdx>>3.
// Each wave (wid = m*4+w) publishes flag[g][wid] = t+1 after ITS h-stores drain (vmcnt(0)).
// All waves poll all 128 flags (2 loads/lane). Single __syncthreads per step (after LDS
// h-stage) — safe: the poll gates waves so no barrier-instance mixing can occur.
__global__ void __launch_bounds__(256, 1) lstm_pk(
    const unsigned short* __restrict__ Xcat,
    const unsigned short* __restrict__ Wcat,
    const float* __restrict__ bias_cat,
    unsigned int* __restrict__ hbuf32,
    ull* __restrict__ flg,
    unsigned int* __restrict__ ctr){
  __shared__ __align__(16) char actb[32768];   // h tile double buffer
  __shared__ int okf, sdead;
  int tid = threadIdx.x;
  int lane = tid & 63, w = tid >> 6;
  int g = blockIdx.x & 7, m = blockIdx.x >> 3;

  // stationary weights: lane holds A-frags for cols 64m+16w+(lane&15), k = s*32+(lane>>4)*8
  int colg = 64*m + 16*w + (lane & 15);
  bf16x8 wf[32];
  {
    const bf16x8* wsrc = (const bf16x8*)(Wcat + colg*1024 + (lane>>4)*8);
    #pragma unroll
    for (int s=0;s<32;s++) wf[s] = wsrc[s*4];
    // pin fragments in VGPRs: opaque asm defeats load re-materialization in the loop
    #pragma unroll
    for (int s=0;s<32;s++) asm volatile("" : "+v"(wf[s]));
  }
  int cb = 64*m + 16*w + 4*(lane>>4);
  f32x4 bias4;
  bias4.x = bias_cat[cb+0]; bias4.y = bias_cat[cb+1];
  bias4.z = bias_cat[cb+2]; bias4.w = bias_cat[cb+3];

  // co-residency check (bounded; no hang)
  if (tid == 0){
    __hip_atomic_fetch_add(&ctr[255], 1u, __ATOMIC_RELAXED, __HIP_MEMORY_SCOPE_AGENT);
    unsigned v = 0; int it = 0;
    do {
      v = __hip_atomic_load(&ctr[255], __ATOMIC_RELAXED, __HIP_MEMORY_SCOPE_AGENT);
      if (v >= 256u) break;
      __builtin_amdgcn_s_sleep(8);
    } while (++it < 2000000);
    okf = (v >= 256u) ? 1 : 0;
    sdead = 0;
  }
  __syncthreads();
  if (!okf) return;

  float cst = 0.f;
  int r16 = tid >> 4, q16 = tid & 15;
  ull* f8 = flg + g*128;
  unsigned int* myflag = (unsigned int*)(f8 + (m*4 + w));

  // prologue: x-part for t=0
  f32x4 acc0, acc1;
  {
    bf16x8 xf[16];
    const bf16x8* xsrc = (const bf16x8*)(Xcat + ((long)0*128 + g*16 + (lane&15))*512 + (lane>>4)*8);
    #pragma unroll
    for (int s=0;s<16;s++) xf[s] = xsrc[s*4];
    acc0 = bias4;
    acc1.x=0.f; acc1.y=0.f; acc1.z=0.f; acc1.w=0.f;
    #pragma unroll
    for (int s=0;s<16;s+=2){
      acc0 = __builtin_amdgcn_mfma_f32_16x16x32_bf16(wf[s],   xf[s],   acc0, 0, 0, 0);
      acc1 = __builtin_amdgcn_mfma_f32_16x16x32_bf16(wf[s+1], xf[s+1], acc1, 0, 0, 0);
    }
  }

  #pragma unroll 1
  for (int t=0; t<1024; ++t){
    // ---- poll: all 128 producer waves of this group finished step t-1 ----
    if (t > 0){
      unsigned tt = (unsigned)t; int itc = 0;
      for (;;){
        unsigned a = __hip_atomic_load((const unsigned int*)(f8 + lane),      __ATOMIC_RELAXED, __HIP_MEMORY_SCOPE_AGENT);
        unsigned b = __hip_atomic_load((const unsigned int*)(f8 + 64 + lane), __ATOMIC_RELAXED, __HIP_MEMORY_SCOPE_AGENT);
        if (__all((int)(a >= tt)) && __all((int)(b >= tt))) break;
        if ((itc & 127) == 127 && *(volatile int*)&sdead) break;
        if (++itc > 400000){
          *(volatile int*)&sdead = 1;
          __hip_atomic_store(&ctr[252], tt, __ATOMIC_RELAXED, __HIP_MEMORY_SCOPE_AGENT);
          break;
        }
      }
      asm volatile("" ::: "memory");
    }
    // ---- stage h_t: 8x8B per thread -> swizzled LDS (double buffer) ----
    {
      const ull* hb = (const ull*)hbuf32 + ((long)(t&1)*8 + g)*(16*128) + r16*128 + q16;
      ull hv[8];
      #pragma unroll
      for (int i=0;i<8;i++)
        hv[i] = __hip_atomic_load(&hb[i*16], __ATOMIC_RELAXED, __HIP_MEMORY_SCOPE_AGENT);
      char* hl = actb + (t&1)*16384;
      #pragma unroll
      for (int i=0;i<8;i++){
        int byt = (r16*1024 + q16*8 + i*128) ^ ((r16 & 7) << 4);
        *(ull*)(hl + byt) = hv[i];
      }
    }
    __syncthreads();
    if (*(volatile int*)&sdead) break;
    // ---- h-part MFMAs (k=512..1023) ----
    {
      const char* hl = actb + (t&1)*16384;
      #pragma unroll
      for (int s=0;s<16;s+=2){
        int by0 = ((lane&15)*1024 + s*64     + (lane>>4)*16) ^ (((lane&15)&7) << 4);
        int by1 = ((lane&15)*1024 + (s+1)*64 + (lane>>4)*16) ^ (((lane&15)&7) << 4);
        bf16x8 b0 = *(const bf16x8*)(hl + by0);
        bf16x8 b1 = *(const bf16x8*)(hl + by1);
        acc0 = __builtin_amdgcn_mfma_f32_16x16x32_bf16(wf[16+s], b0, acc0, 0, 0, 0);
        acc1 = __builtin_amdgcn_mfma_f32_16x16x32_bf16(wf[17+s], b1, acc1, 0, 0, 0);
      }
    }
    // ---- gates & state update ----
    float gi = acc0.x + acc1.x, gf = acc0.y + acc1.y;
    float gg = acc0.z + acc1.z, go = acc0.w + acc1.w;
    float iv = 1.f / (1.f + __expf(-gi));
    float fv = 1.f / (1.f + __expf(-gf));
    float e2 = __expf(-2.f * gg);
    float gv = (1.f - e2) / (1.f + e2);
    float ov = 1.f / (1.f + __expf(-go));
    cst = fv * cst + iv * gv;
    float e2c = __expf(-2.f * cst);
    float hout = ov * (1.f - e2c) / (1.f + e2c);
    // ---- publish h_{t+1} (packed unit pairs) ----
    {
      unsigned short hb16 = f2bf(hout);
      int partner = __shfl_xor((int)hb16, 16);
      int hi = lane >> 4;
      if ((hi & 1) == 0){
        int ug = 16*m + 4*w + hi;
        int r = lane & 15;
        unsigned pack = (unsigned)hb16 | (((unsigned)partner & 0xFFFFu) << 16);
        unsigned int* dst = hbuf32 + ((long)((t+1)&1)*8 + g)*(16*256) + r*256 + (ug >> 1);
        __hip_atomic_store(dst, pack, __ATOMIC_RELAXED, __HIP_MEMORY_SCOPE_AGENT);
      }
    }
    // drain THIS wave's h stores, then publish its flag (no barrier needed)
    asm volatile("s_waitcnt vmcnt(0)" ::: "memory");
    if (lane == 0)
      __hip_atomic_store(myflag, (unsigned)(t+1), __ATOMIC_RELAXED, __HIP_MEMORY_SCOPE_AGENT);
    // ---- x-part for t+1 (overlaps flag propagation / other waves' tails) ----
    {
      int tn = (t < 1023) ? (t+1) : 1023;
      bf16x8 xf[16];
      const bf16x8* xsrc = (const bf16x8*)(Xcat + ((long)tn*128 + g*16 + (lane&15))*512 + (lane>>4)*8);
      #pragma unroll
      for (int s=0;s<16;s++) xf[s] = xsrc[s*4];
      acc0 = bias4;
      acc1.x=0.f; acc1.y=0.f; acc1.z=0.f; acc1.w=0.f;
      #pragma unroll
      for (int s=0;s<16;s+=2){
        acc0 = __builtin_amdgcn_mfma_f32_16x16x32_bf16(wf[s],   xf[s],   acc0, 0, 0, 0);
        acc1 = __builtin_amdgcn_mfma_f32_16x16x32_bf16(wf[s+1], xf[s+1], acc1, 0, 0, 0);
      }
    }
  }

  __syncthreads();
  if (tid == 0 && !sdead)
    __hip_atomic_fetch_add(&ctr[251], 1u, __ATOMIC_RELAXED, __HIP_MEMORY_SCOPE_AGENT);
}

// ---------------- output projection ----------------
__global__ void __launch_bounds__(256) out_gemm(
    const unsigned short* __restrict__ hbuf, const unsigned int* __restrict__ ctr,
    const float* __restrict__ out_w, const float* __restrict__ out_b,
    float* __restrict__ out){
  unsigned done = ctr[251], arriv = ctr[255], dead = ctr[252];
  if (dead != 0u || done != 256u){
    float v = dead ? (20000.f + (float)dead) : (10000.f + (float)arriv);
    if (threadIdx.x < 32) out[blockIdx.x*32 + threadIdx.x] = v;
    return;
  }
  __shared__ float part[8][32];
  int b = blockIdx.x;
  int g = b >> 4, r = b & 15;
  const unsigned short* hrow = hbuf + ((long)g*16 + r)*512;   // buf 0 holds h after step 1023
  int col = threadIdx.x & 31, p = threadIdx.x >> 5;
  float s = 0.f;
  for (int u = p*64; u < p*64 + 64; ++u)
    s += bf2f(hrow[u]) * out_w[col*512 + u];
  part[p][col] = s;
  __syncthreads();
  if (p == 0){
    float t = out_b[col];
    #pragma unroll
    for (int i=0;i<8;i++) t += part[i][col];
    out[b*32 + col] = t;
  }
}

extern "C" void kernel_launch(void* const* d_in, const int* in_sizes, int n_in,
                              void* d_out, int out_size, void* d_ws, size_t ws_size,
                              hipStream_t stream){
  const float* x_num   = (const float*)d_in[0];
  const int*   x_state = (const int*)d_in[1];
  const float* num_w0  = (const float*)d_in[2];
  const float* num_b0  = (const float*)d_in[3];
  const float* num_w1  = (const float*)d_in[4];
  const float* num_b1  = (const float*)d_in[5];
  const float* emb     = (const float*)d_in[6];
  const float* st_w0   = (const float*)d_in[7];
  const float* st_b0   = (const float*)d_in[8];
  const float* st_w1   = (const float*)d_in[9];
  const float* st_b1   = (const float*)d_in[10];
  const float* Wii = (const float*)d_in[11];
  const float* Whi = (const float*)d_in[12];
  const float* Wif = (const float*)d_in[13];
  const float* Whf = (const float*)d_in[14];
  const float* Wig = (const float*)d_in[15];
  const float* Whg = (const float*)d_in[16];
  const float* Wio = (const float*)d_in[17];
  const float* Who = (const float*)d_in[18];
  const float* Bii = (const float*)d_in[19];
  const float* Bhi = (const float*)d_in[20];
  const float* Bif = (const float*)d_in[21];
  const float* Bhf = (const float*)d_in[22];
  const float* Big = (const float*)d_in[23];
  const float* Bhg = (const float*)d_in[24];
  const float* Bio = (const float*)d_in[25];
  const float* Bho = (const float*)d_in[26];
  const float* out_w = (const float*)d_in[27];
  const float* out_b = (const float*)d_in[28];

  float* out = (float*)d_out;

  // sentinel: if later launches silently fail, absmax ~= 50000
  diag_write<<<16, 256, 0, stream>>>(out, 50000.f);

  if (ws_size < WS_NEED){
    diag_write<<<16, 256, 0, stream>>>(out, 100000.f + (float)(ws_size >> 20));
    return;
  }

  char* ws = (char*)d_ws;
  unsigned short* Xcat = (unsigned short*)(ws + OFF_XCAT);
  unsigned short* Wcat = (unsigned short*)(ws + OFF_WCAT);
  float* bias_cat      = (float*)(ws + OFF_BIAS);
  unsigned int* hbuf32 = (unsigned int*)(ws + OFF_HBUF);
  ull* flg             = (ull*)(ws + OFF_FLAG);
  unsigned int* ctr    = (unsigned int*)(ws + OFF_CTR);

  // zero h double-buffer + flags + counters every call (graph-replay determinism)
  hipMemsetAsync(ws + OFF_HBUF, 0, 262144 + 8192 + 1024, stream);

  prep_w<<<8192, 256, 0, stream>>>(Wii, Wif, Wig, Wio, Whi, Whf, Whg, Who,
                                   Bii, Bif, Big, Bio, Bhi, Bhf, Bhg, Bho,
                                   Wcat, bias_cat);

  stageA_fused<<<8192, 256, 0, stream>>>(x_num, x_state, emb,
                                         num_w0, num_b0, num_w1, num_b1,
                                         st_w0, st_b0, st_w1, st_b1, Xcat);

  lstm_pk<<<256, 256, 0, stream>>>(Xcat, Wcat, bias_cat, hbuf32, flg, ctr);

  out_gemm<<<128, 256, 0, stream>>>((const unsigned short*)hbuf32, ctr, out_w, out_b, out);
}